// Round 9
// baseline (414.626 us; speedup 1.0000x reference)
//
#include <hip/hip_runtime.h>
#include <math.h>

typedef _Float16 f16;
typedef _Float16 f16x8 __attribute__((ext_vector_type(8)));
typedef float f32x4 __attribute__((ext_vector_type(4)));

#define N_NODES 50000
#define N_EDGES 800000
#define HID 64
#define HEADS 8
#define DH 8
#define LAYERS 6
#define EDGE_DIM 16
#define SIGN_DIM 8
#define NSIGN 3
#define VOC 512
#define NCOMB (VOC * NSIGN)
#define EPS 1e-5f

// coarse-bucket sort params
#define NBUCK 196
#define BUCK_CAP 5120
#define BIN_EPB 4096
#define BIN_EPT 16
#define BIN_NBLK ((N_EDGES + BIN_EPB - 1) / BIN_EPB)

// prep kernel grid ranges
#define WP_BLK 384
#define TE_BLK (LAYERS * (NCOMB / 16))
#define PREP_BLK (WP_BLK + TE_BLK + 1)

__device__ __forceinline__ float dot8(f16x8 a, f16x8 b, float c) {
#if __has_builtin(__builtin_amdgcn_fdot2)
    c = __builtin_amdgcn_fdot2(__builtin_shufflevector(a, a, 0, 1),
                               __builtin_shufflevector(b, b, 0, 1), c, false);
    c = __builtin_amdgcn_fdot2(__builtin_shufflevector(a, a, 2, 3),
                               __builtin_shufflevector(b, b, 2, 3), c, false);
    c = __builtin_amdgcn_fdot2(__builtin_shufflevector(a, a, 4, 5),
                               __builtin_shufflevector(b, b, 4, 5), c, false);
    c = __builtin_amdgcn_fdot2(__builtin_shufflevector(a, a, 6, 7),
                               __builtin_shufflevector(b, b, 6, 7), c, false);
#else
#pragma unroll
    for (int i = 0; i < 8; ++i) c += (float)a[i] * (float)b[i];
#endif
    return c;
}

// ---------------- prep: weight prep + TE table + inits
__global__ __launch_bounds__(256) void k_prep(
    const float* __restrict__ Wq, const float* __restrict__ bq,
    const float* __restrict__ Wk, const float* __restrict__ bk,
    const float* __restrict__ Wv, const float* __restrict__ bv,
    const float* __restrict__ Ws, const float* __restrict__ bs,
    f16* __restrict__ wcatT, float* __restrict__ bcat,
    const float* __restrict__ emb_s, const float* __restrict__ emb_sg,
    const float* __restrict__ We, const float* __restrict__ be,
    const float* __restrict__ Wedge, f16* __restrict__ TE,
    int* __restrict__ bcur, int* __restrict__ rowptr,
    float* __restrict__ gsumR) {
    int b = blockIdx.x;
    int t = threadIdx.x;
    if (b < WP_BLK) {
        int idx = b * 256 + t;
        int l = idx >> 14;
        int r = idx & 16383;
        int c = r >> 6, kk = r & 63;
        int m = c >> 6, cc = c & 63;
        const float* W = (m == 0) ? Wq : (m == 1) ? Wk : (m == 2) ? Wv : Ws;
        wcatT[idx] = (f16)W[l * 4096 + kk * 64 + cc];
        if (kk == 0) {
            const float* B = (m == 0) ? bq : (m == 1) ? bk : (m == 2) ? bv : bs;
            bcat[l * 256 + c] = B[l * 64 + cc];
        }
        return;
    }
    b -= WP_BLK;
    if (b < TE_BLK) {
        __shared__ float T[16][16];
        int l = b / (NCOMB / 16);
        int comb0 = (b % (NCOMB / 16)) * 16;
        int cl = t >> 4, c = t & 15;
        int comb = comb0 + cl;
        int lb = comb / NSIGN, sg = comb % NSIGN;
        float acc = be[c];
        const float* er = emb_s + lb * HID;
#pragma unroll
        for (int j = 0; j < HID; ++j) acc += er[j] * We[j * EDGE_DIM + c];
        const float* sr = emb_sg + sg * SIGN_DIM;
#pragma unroll
        for (int j = 0; j < SIGN_DIM; ++j) acc += sr[j] * We[(HID + j) * EDGE_DIM + c];
        T[cl][c] = acc;
        __syncthreads();
        const float* w = Wedge + l * EDGE_DIM * HID;
#pragma unroll
        for (int rep = 0; rep < 4; ++rep) {
            int idx = rep * 256 + t;
            int cml = idx >> 6, d = idx & 63;
            float a = 0.f;
#pragma unroll
            for (int j = 0; j < EDGE_DIM; ++j) a += T[cml][j] * w[j * HID + d];
            TE[((size_t)l * NCOMB + comb0 + cml) * HID + d] = (f16)a;
        }
        return;
    }
    if (t < NBUCK) bcur[t] = 0;
    for (int i = t; i < 512; i += 256) gsumR[i] = 0.f;
    if (t == 0) rowptr[N_NODES] = N_EDGES;
}

// ---------------- node features + layer-0 projection (16 nodes/block)
__global__ __launch_bounds__(256) void k_nfproj(
    const int* __restrict__ xn, const float* __restrict__ emb_s,
    const float* __restrict__ emb_p, const f16* __restrict__ wcatT0,
    const float* __restrict__ bcat0,
    f16* __restrict__ q, f16* __restrict__ kv, f16* __restrict__ sk) {
    __shared__ __align__(16) f16 xs[16][72];
    int t = threadIdx.x;
    int n0 = blockIdx.x * 16;
#pragma unroll
    for (int i = 0; i < 4; ++i) {
        int idx = i * 256 + t;
        int row = idx >> 6, col = idx & 63;
        int n = n0 + row;
        float acc = 0.f;
#pragma unroll
        for (int s = 0; s < 4; ++s) {
            int id = xn[n * 4 + s];
            acc += emb_s[id * HID + col] + emb_p[s * HID + col];
        }
        xs[row][col] = (f16)acc;
    }
    __syncthreads();
    int w = t >> 6, l = t & 63;
    int rowA = l & 15;
    int kb = l >> 4;
    f16x8 a0 = *(const f16x8*)(&xs[rowA][kb << 3]);
    f16x8 a1 = *(const f16x8*)(&xs[rowA][32 + (kb << 3)]);
    int c0 = w << 6;
    int rbase = n0 + ((l >> 4) << 2);
#pragma unroll
    for (int tt = 0; tt < 4; ++tt) {
        int cl = c0 + tt * 16 + (l & 15);
        const f16* wr = wcatT0 + (cl << 6) + (kb << 3);
        f16x8 b0 = *(const f16x8*)(wr);
        f16x8 b1 = *(const f16x8*)(wr + 32);
        f32x4 z = {0.f, 0.f, 0.f, 0.f};
        z = __builtin_amdgcn_mfma_f32_16x16x32_f16(a0, b0, z, 0, 0, 0);
        z = __builtin_amdgcn_mfma_f32_16x16x32_f16(a1, b1, z, 0, 0, 0);
        float bb = bcat0[cl];
        int cc = cl & 63;
        int m = cl >> 6;
#pragma unroll
        for (int r = 0; r < 4; ++r) {
            int n = rbase + r;
            f16 val = (f16)(z[r] + bb);
            if (m == 0) q[(n << 6) + cc] = val;
            else if (m == 1) kv[(size_t)n * 128 + cc] = val;
            else if (m == 2) kv[(size_t)n * 128 + 64 + cc] = val;
            else sk[(n << 6) + cc] = val;
        }
    }
}

// ---------------- phase 1: bin edges into coarse buckets
__global__ __launch_bounds__(256) void k_bin(
    const int* __restrict__ src, const int* __restrict__ dst,
    const int* __restrict__ label, const int* __restrict__ sign,
    int* __restrict__ bcur, int2* __restrict__ buf) {
    __shared__ int hist[NBUCK];
    __shared__ int base[NBUCK];
    int t = threadIdx.x;
    for (int i = t; i < NBUCK; i += 256) hist[i] = 0;
    __syncthreads();
    int e0 = blockIdx.x * BIN_EPB;
    int pk[BIN_EPT], dl[BIN_EPT], bl[BIN_EPT], loc[BIN_EPT];
#pragma unroll
    for (int i = 0; i < BIN_EPT; ++i) {
        int e = e0 + i * 256 + t;
        bool vld = e < N_EDGES;
        int d = vld ? dst[e] : 0;
        bl[i] = d >> 8;
        dl[i] = d & 255;
        pk[i] = vld ? ((src[e] << 11) | (label[e] * NSIGN + sign[e])) : 0;
        loc[i] = vld ? atomicAdd(&hist[bl[i]], 1) : -1;
    }
    __syncthreads();
    if (t < NBUCK) {
        int h = hist[t];
        int gb = h ? atomicAdd(&bcur[t], h) : 0;
        base[t] = t * BUCK_CAP + gb;
    }
    __syncthreads();
#pragma unroll
    for (int i = 0; i < BIN_EPT; ++i)
        if (loc[i] >= 0) buf[base[bl[i]] + loc[i]] = make_int2(pk[i], dl[i]);
}

// ---------------- phase 2: inline bucket scan + per-bucket rowptr + CSR scatter
__global__ __launch_bounds__(256) void k_place(
    const int* __restrict__ bcur, const int2* __restrict__ buf,
    int* __restrict__ rowptr, int* __restrict__ scomb) {
    __shared__ int hist[256];
    __shared__ int curs[256];
    __shared__ int wsA[4];
    __shared__ int wsB[4];
    __shared__ int sbase;
    int t = threadIdx.x, b = blockIdx.x;
    int lane = t & 63, w = t >> 6;
    int v = (t < NBUCK) ? bcur[t] : 0;
    int incl = v;
#pragma unroll
    for (int o = 1; o < 64; o <<= 1) {
        int u = __shfl_up(incl, o);
        if (lane >= o) incl += u;
    }
    if (lane == 63) wsA[w] = incl;
    hist[t] = 0;
    __syncthreads();
    int woff = 0;
    for (int j = 0; j < w; ++j) woff += wsA[j];
    if (t == b) sbase = woff + incl - v;
    __syncthreads();
    int cnt = bcur[b];
    const int2* bb = buf + (size_t)b * BUCK_CAP;
    for (int i = t; i < cnt; i += 256) atomicAdd(&hist[bb[i].y], 1);
    __syncthreads();
    int hv = hist[t];
    int hincl = hv;
#pragma unroll
    for (int o = 1; o < 64; o <<= 1) {
        int u = __shfl_up(hincl, o);
        if (lane >= o) hincl += u;
    }
    if (lane == 63) wsB[w] = hincl;
    __syncthreads();
    int hoff = 0;
    for (int j = 0; j < w; ++j) hoff += wsB[j];
    int start = sbase + hoff + hincl - hv;
    int n = (b << 8) + t;
    if (n < N_NODES) rowptr[n] = start;
    curs[t] = start;
    __syncthreads();
    for (int i = t; i < cnt; i += 256) {
        int2 r = bb[i];
        int pos = atomicAdd(&curs[r.y], 1);
        scomb[pos] = r.x;
    }
}

// ---------------- MFMA projection (layers 1..5): x16 -> q, kv, sk
__global__ __launch_bounds__(256) void k_proj(
    const f16* __restrict__ x16, const f16* __restrict__ wcatT_l,
    const float* __restrict__ bcat_l,
    f16* __restrict__ q, f16* __restrict__ kv, f16* __restrict__ sk) {
    int t = threadIdx.x;
    int w = t >> 6, l = t & 63;
    int n0 = blockIdx.x * 16;
    int rowA = n0 + (l & 15);
    int kb = l >> 4;
    const f16* xr = x16 + (rowA << 6) + (kb << 3);
    f16x8 a0 = *(const f16x8*)(xr);
    f16x8 a1 = *(const f16x8*)(xr + 32);
    int c0 = w << 6;
    int rbase = n0 + ((l >> 4) << 2);
#pragma unroll
    for (int tt = 0; tt < 4; ++tt) {
        int cl = c0 + tt * 16 + (l & 15);
        const f16* wr = wcatT_l + (cl << 6) + (kb << 3);
        f16x8 b0 = *(const f16x8*)(wr);
        f16x8 b1 = *(const f16x8*)(wr + 32);
        f32x4 z = {0.f, 0.f, 0.f, 0.f};
        z = __builtin_amdgcn_mfma_f32_16x16x32_f16(a0, b0, z, 0, 0, 0);
        z = __builtin_amdgcn_mfma_f32_16x16x32_f16(a1, b1, z, 0, 0, 0);
        float bb = bcat_l[cl];
        int cc = cl & 63;
#pragma unroll
        for (int r = 0; r < 4; ++r) {
            int n = rbase + r;
            f16 val = (f16)(z[r] + bb);
            if (w == 0) q[(n << 6) + cc] = val;
            else if (w == 1) kv[(size_t)n * 128 + cc] = val;
            else if (w == 2) kv[(size_t)n * 128 + 64 + cc] = val;
            else sk[(n << 6) + cc] = val;
        }
    }
}

// ---------------- shared aggregation core: 32 edges/iteration (4 slots/lane)
#define AGG_BODY()                                                               \
    int e = lane >> 3;                                                           \
    int h = lane & 7;                                                            \
    int d = (h << 3) + e;                                                        \
    float skv = (float)sk[(n << 6) + d];                                         \
    f16x8 qf = *(const f16x8*)(q + (n << 6) + (h << 3));                         \
    int rs = rowptr[n], re = rowptr[n + 1];                                      \
    const float scale = 0.35355339059327373f;                                    \
    float lsum = 0.f;                                                            \
    float acc0 = 0.f, acc1 = 0.f, acc2 = 0.f, acc3 = 0.f;                        \
    float acc4 = 0.f, acc5 = 0.f, acc6 = 0.f, acc7 = 0.f;                        \
    for (int j0 = rs; j0 < re; j0 += 32) {                                       \
        int ja = j0 + e, jb = ja + 8, jc = ja + 16, jd = ja + 24;                \
        bool va = ja < re, vb = jb < re, vc = jc < re, vd = jd < re;             \
        int pa = scomb[va ? ja : rs];                                            \
        int pb = scomb[vb ? jb : rs];                                            \
        int pc = scomb[vc ? jc : rs];                                            \
        int pd = scomb[vd ? jd : rs];                                            \
        const f16* kpa = kv + ((size_t)(pa >> 11) << 7) + (h << 3);              \
        const f16* kpb = kv + ((size_t)(pb >> 11) << 7) + (h << 3);              \
        const f16* kpc = kv + ((size_t)(pc >> 11) << 7) + (h << 3);              \
        const f16* kpd = kv + ((size_t)(pd >> 11) << 7) + (h << 3);              \
        f16x8 ka = *(const f16x8*)(kpa);                                         \
        f16x8 vaf = *(const f16x8*)(kpa + 64);                                   \
        f16x8 ta = *(const f16x8*)(te + ((pa & 2047) << 6) + (h << 3));          \
        f16x8 kb2 = *(const f16x8*)(kpb);                                        \
        f16x8 vbf = *(const f16x8*)(kpb + 64);                                   \
        f16x8 tb = *(const f16x8*)(te + ((pb & 2047) << 6) + (h << 3));          \
        f16x8 kc = *(const f16x8*)(kpc);                                         \
        f16x8 vcf = *(const f16x8*)(kpc + 64);                                   \
        f16x8 tc = *(const f16x8*)(te + ((pc & 2047) << 6) + (h << 3));          \
        f16x8 kd = *(const f16x8*)(kpd);                                         \
        f16x8 vdf = *(const f16x8*)(kpd + 64);                                   \
        f16x8 td = *(const f16x8*)(te + ((pd & 2047) << 6) + (h << 3));          \
        float ala = dot8(qf, ka + ta, 0.f) * scale;                              \
        float alb = dot8(qf, kb2 + tb, 0.f) * scale;                             \
        float alc = dot8(qf, kc + tc, 0.f) * scale;                              \
        float ald = dot8(qf, kd + td, 0.f) * scale;                              \
        float wa = va ? __expf(ala) : 0.f;                                       \
        float wb = vb ? __expf(alb) : 0.f;                                       \
        float wc = vc ? __expf(alc) : 0.f;                                       \
        float wd = vd ? __expf(ald) : 0.f;                                       \
        lsum += (wa + wb) + (wc + wd);                                           \
        f16x8 vta = vaf + ta;                                                    \
        f16x8 vtb = vbf + tb;                                                    \
        f16x8 vtc = vcf + tc;                                                    \
        f16x8 vtd = vdf + td;                                                    \
        acc0 += wa * (float)vta[0] + wb * (float)vtb[0] + wc * (float)vtc[0] + wd * (float)vtd[0]; \
        acc1 += wa * (float)vta[1] + wb * (float)vtb[1] + wc * (float)vtc[1] + wd * (float)vtd[1]; \
        acc2 += wa * (float)vta[2] + wb * (float)vtb[2] + wc * (float)vtc[2] + wd * (float)vtd[2]; \
        acc3 += wa * (float)vta[3] + wb * (float)vtb[3] + wc * (float)vtc[3] + wd * (float)vtd[3]; \
        acc4 += wa * (float)vta[4] + wb * (float)vtb[4] + wc * (float)vtc[4] + wd * (float)vtd[4]; \
        acc5 += wa * (float)vta[5] + wb * (float)vtb[5] + wc * (float)vtc[5] + wd * (float)vtd[5]; \
        acc6 += wa * (float)vta[6] + wb * (float)vtb[6] + wc * (float)vtc[6] + wd * (float)vtd[6]; \
        acc7 += wa * (float)vta[7] + wb * (float)vtb[7] + wc * (float)vtc[7] + wd * (float)vtd[7]; \
    }                                                                            \
    _Pragma("unroll")                                                            \
    for (int o = 8; o < 64; o <<= 1) {                                           \
        lsum += __shfl_xor(lsum, o);                                             \
        acc0 += __shfl_xor(acc0, o);                                             \
        acc1 += __shfl_xor(acc1, o);                                             \
        acc2 += __shfl_xor(acc2, o);                                             \
        acc3 += __shfl_xor(acc3, o);                                             \
        acc4 += __shfl_xor(acc4, o);                                             \
        acc5 += __shfl_xor(acc5, o);                                             \
        acc6 += __shfl_xor(acc6, o);                                             \
        acc7 += __shfl_xor(acc7, o);                                             \
    }                                                                            \
    float av = acc0;                                                             \
    av = (e == 1) ? acc1 : av;                                                   \
    av = (e == 2) ? acc2 : av;                                                   \
    av = (e == 3) ? acc3 : av;                                                   \
    av = (e == 4) ? acc4 : av;                                                   \
    av = (e == 5) ? acc5 : av;                                                   \
    av = (e == 6) ? acc6 : av;                                                   \
    av = (e == 7) ? acc7 : av;                                                   \
    float outv = av / (lsum + 1e-16f) + skv;

// ---------------- aggregation + skip + LN/ReLU (layers 0..4)
__global__ __launch_bounds__(256) void k_aggL(
    const f16* __restrict__ q, const f16* __restrict__ kv,
    const f16* __restrict__ sk, const f16* __restrict__ te,
    const int* __restrict__ scomb, const int* __restrict__ rowptr,
    const float* __restrict__ ln_g, const float* __restrict__ ln_b,
    f16* __restrict__ xout) {
    int t = threadIdx.x;
    int wid = t >> 6, lane = t & 63;
    int n = blockIdx.x * 4 + wid;
    AGG_BODY()
    float ssum = outv;
#pragma unroll
    for (int o = 1; o < 64; o <<= 1) ssum += __shfl_xor(ssum, o);
    float mu = ssum * (1.f / 64.f);
    float dv = outv - mu;
    float vs = dv * dv;
#pragma unroll
    for (int o = 1; o < 64; o <<= 1) vs += __shfl_xor(vs, o);
    float var = vs * (1.f / 64.f);
    float yv = ln_g[d] * dv / sqrtf(var + EPS) + ln_b[d];
    xout[(n << 6) + d] = (f16)fmaxf(yv, 0.f);
}

// ---------------- final-layer aggregation + policy head + fused column sums
__global__ __launch_bounds__(256) void k_aggF(
    const f16* __restrict__ q, const f16* __restrict__ kv,
    const f16* __restrict__ sk, const f16* __restrict__ te,
    const int* __restrict__ scomb, const int* __restrict__ rowptr,
    const float* __restrict__ Wp, const float* __restrict__ bp,
    float* __restrict__ pol, float* __restrict__ gsumR) {
    __shared__ float sh[4][64];
    int t = threadIdx.x;
    int wid = t >> 6, lane = t & 63;
    int n = blockIdx.x * 4 + wid;
    AGG_BODY()
    float p0 = outv * Wp[d * 2 + 0];
    float p1 = outv * Wp[d * 2 + 1];
#pragma unroll
    for (int o = 1; o < 64; o <<= 1) {
        p0 += __shfl_xor(p0, o);
        p1 += __shfl_xor(p1, o);
    }
    if (lane == 0) {
        pol[n * 2 + 0] = p0 + bp[0];
        pol[n * 2 + 1] = p1 + bp[1];
    }
    sh[wid][d] = outv;
    __syncthreads();
    if (wid == 0) {
        float s = sh[0][lane] + sh[1][lane] + sh[2][lane] + sh[3][lane];
        atomicAdd(&gsumR[((blockIdx.x & 7) << 6) + lane], s);
    }
}

// ---------------- value head
__global__ __launch_bounds__(64) void k_value(
    const float* __restrict__ gsumR, const float* __restrict__ Wv1,
    const float* __restrict__ bv1, const float* __restrict__ Wv2,
    const float* __restrict__ bv2, float* __restrict__ out) {
    int lane = threadIdx.x;
    __shared__ float g[64];
    float gs = 0.f;
#pragma unroll
    for (int r = 0; r < 8; ++r) gs += gsumR[(r << 6) + lane];
    g[lane] = gs * (1.f / N_NODES);
    __syncthreads();
    float h = bv1[lane];
    for (int i = 0; i < HID; ++i) h += g[i] * Wv1[i * HID + lane];
    h = fmaxf(h, 0.f);
    float p = h * Wv2[lane];
#pragma unroll
    for (int o = 1; o < 64; o <<= 1) p += __shfl_xor(p, o);
    if (lane == 0) out[0] = tanhf(p + bv2[0]);
}

extern "C" void kernel_launch(void* const* d_in, const int* in_sizes, int n_in,
                              void* d_out, int out_size, void* d_ws, size_t ws_size,
                              hipStream_t stream) {
    const int* x_nodes = (const int*)d_in[0];
    const int* edge_index = (const int*)d_in[1];
    const int* edge_label = (const int*)d_in[2];
    const int* edge_sign = (const int*)d_in[3];
    const float* emb_strand = (const float*)d_in[4];
    const float* emb_pos = (const float*)d_in[5];
    const float* emb_sign = (const float*)d_in[6];
    const float* We = (const float*)d_in[7];
    const float* be = (const float*)d_in[8];
    const float* Wq = (const float*)d_in[9];
    const float* bq = (const float*)d_in[10];
    const float* Wk = (const float*)d_in[11];
    const float* bk = (const float*)d_in[12];
    const float* Wv = (const float*)d_in[13];
    const float* bv = (const float*)d_in[14];
    const float* Wedge = (const float*)d_in[15];
    const float* Wskip = (const float*)d_in[16];
    const float* bskip = (const float*)d_in[17];
    const float* ln_g = (const float*)d_in[18];
    const float* ln_b = (const float*)d_in[19];
    const float* Wp = (const float*)d_in[20];
    const float* bp = (const float*)d_in[21];
    const float* Wv1 = (const float*)d_in[22];
    const float* bv1 = (const float*)d_in[23];
    const float* Wv2 = (const float*)d_in[24];
    const float* bv2 = (const float*)d_in[25];
    float* out = (float*)d_out;

    const int* src = edge_index;
    const int* dst = edge_index + N_EDGES;

    char* ws = (char*)d_ws;
    size_t off = 0;
    auto alloc = [&](size_t bytes) -> void* {
        void* p = ws + off;
        off += (bytes + 255) & ~(size_t)255;
        return p;
    };
    f16* x16 = (f16*)alloc((size_t)N_NODES * HID * 2);
    f16* q = (f16*)alloc((size_t)N_NODES * HID * 2);
    f16* kv = (f16*)alloc((size_t)N_NODES * 128 * 2);
    f16* sk = (f16*)alloc((size_t)N_NODES * HID * 2);
    int* scomb = (int*)alloc((size_t)N_EDGES * 4);
    int2* binbuf = (int2*)alloc((size_t)NBUCK * BUCK_CAP * 8);
    int* rowptr = (int*)alloc((size_t)(N_NODES + 1) * 4);
    int* bcur = (int*)alloc((size_t)NBUCK * 4);
    f16* TE = (f16*)alloc((size_t)LAYERS * NCOMB * HID * 2);
    f16* wcatT = (f16*)alloc((size_t)LAYERS * 256 * HID * 2);
    float* bcat = (float*)alloc((size_t)LAYERS * 256 * 4);
    float* gsumR = (float*)alloc(512 * 4);

    k_prep<<<PREP_BLK, 256, 0, stream>>>(
        Wq, bq, Wk, bk, Wv, bv, Wskip, bskip, wcatT, bcat,
        emb_strand, emb_sign, We, be, Wedge, TE, bcur, rowptr, gsumR);
    k_nfproj<<<N_NODES / 16, 256, 0, stream>>>(
        x_nodes, emb_strand, emb_pos, wcatT, bcat, q, kv, sk);
    k_bin<<<BIN_NBLK, 256, 0, stream>>>(src, dst, edge_label, edge_sign, bcur, binbuf);
    k_place<<<NBUCK, 256, 0, stream>>>(bcur, binbuf, rowptr, scomb);

    for (int l = 0; l < LAYERS - 1; ++l) {
        k_aggL<<<N_NODES / 4, 256, 0, stream>>>(
            q, kv, sk, TE + (size_t)l * NCOMB * HID, scomb, rowptr,
            ln_g + (size_t)l * HID, ln_b + (size_t)l * HID, x16);
        k_proj<<<N_NODES / 16, 256, 0, stream>>>(
            x16, wcatT + (size_t)(l + 1) * 256 * HID, bcat + (size_t)(l + 1) * 256,
            q, kv, sk);
    }
    k_aggF<<<N_NODES / 4, 256, 0, stream>>>(
        q, kv, sk, TE + (size_t)(LAYERS - 1) * NCOMB * HID, scomb, rowptr,
        Wp, bp, out, gsumR);
    k_value<<<1, 64, 0, stream>>>(gsumR, Wv1, bv1, Wv2, bv2, out + 2 * N_NODES);
}

// Round 10
// 388.198 us; speedup vs baseline: 1.0681x; 1.0681x over previous
//
#include <hip/hip_runtime.h>
#include <math.h>

typedef _Float16 f16;
typedef _Float16 f16x8 __attribute__((ext_vector_type(8)));
typedef float f32x4 __attribute__((ext_vector_type(4)));

#define N_NODES 50000
#define N_EDGES 800000
#define HID 64
#define HEADS 8
#define DH 8
#define LAYERS 6
#define EDGE_DIM 16
#define SIGN_DIM 8
#define NSIGN 3
#define VOC 512
#define NCOMB (VOC * NSIGN)
#define EPS 1e-5f

// coarse-bucket sort params
#define NBUCK 196
#define BUCK_CAP 5120
#define BIN_EPB 4096
#define BIN_EPT 16
#define BIN_NBLK ((N_EDGES + BIN_EPB - 1) / BIN_EPB)

// prep kernel grid ranges
#define WP_BLK 384
#define TE_BLK (LAYERS * (NCOMB / 16))
#define PREP_BLK (WP_BLK + TE_BLK + 1)

__device__ __forceinline__ float dot8(f16x8 a, f16x8 b, float c) {
#if __has_builtin(__builtin_amdgcn_fdot2)
    c = __builtin_amdgcn_fdot2(__builtin_shufflevector(a, a, 0, 1),
                               __builtin_shufflevector(b, b, 0, 1), c, false);
    c = __builtin_amdgcn_fdot2(__builtin_shufflevector(a, a, 2, 3),
                               __builtin_shufflevector(b, b, 2, 3), c, false);
    c = __builtin_amdgcn_fdot2(__builtin_shufflevector(a, a, 4, 5),
                               __builtin_shufflevector(b, b, 4, 5), c, false);
    c = __builtin_amdgcn_fdot2(__builtin_shufflevector(a, a, 6, 7),
                               __builtin_shufflevector(b, b, 6, 7), c, false);
#else
#pragma unroll
    for (int i = 0; i < 8; ++i) c += (float)a[i] * (float)b[i];
#endif
    return c;
}

// ---------------- prep: weight prep + TE table + inits
__global__ __launch_bounds__(256) void k_prep(
    const float* __restrict__ Wq, const float* __restrict__ bq,
    const float* __restrict__ Wk, const float* __restrict__ bk,
    const float* __restrict__ Wv, const float* __restrict__ bv,
    const float* __restrict__ Ws, const float* __restrict__ bs,
    f16* __restrict__ wcatT, float* __restrict__ bcat,
    const float* __restrict__ emb_s, const float* __restrict__ emb_sg,
    const float* __restrict__ We, const float* __restrict__ be,
    const float* __restrict__ Wedge, f16* __restrict__ TE,
    int* __restrict__ bcur, int* __restrict__ rowptr,
    float* __restrict__ gsumR) {
    int b = blockIdx.x;
    int t = threadIdx.x;
    if (b < WP_BLK) {
        int idx = b * 256 + t;
        int l = idx >> 14;
        int r = idx & 16383;
        int c = r >> 6, kk = r & 63;
        int m = c >> 6, cc = c & 63;
        const float* W = (m == 0) ? Wq : (m == 1) ? Wk : (m == 2) ? Wv : Ws;
        wcatT[idx] = (f16)W[l * 4096 + kk * 64 + cc];
        if (kk == 0) {
            const float* B = (m == 0) ? bq : (m == 1) ? bk : (m == 2) ? bv : bs;
            bcat[l * 256 + c] = B[l * 64 + cc];
        }
        return;
    }
    b -= WP_BLK;
    if (b < TE_BLK) {
        __shared__ float T[16][16];
        int l = b / (NCOMB / 16);
        int comb0 = (b % (NCOMB / 16)) * 16;
        int cl = t >> 4, c = t & 15;
        int comb = comb0 + cl;
        int lb = comb / NSIGN, sg = comb % NSIGN;
        float acc = be[c];
        const float* er = emb_s + lb * HID;
#pragma unroll
        for (int j = 0; j < HID; ++j) acc += er[j] * We[j * EDGE_DIM + c];
        const float* sr = emb_sg + sg * SIGN_DIM;
#pragma unroll
        for (int j = 0; j < SIGN_DIM; ++j) acc += sr[j] * We[(HID + j) * EDGE_DIM + c];
        T[cl][c] = acc;
        __syncthreads();
        const float* w = Wedge + l * EDGE_DIM * HID;
#pragma unroll
        for (int rep = 0; rep < 4; ++rep) {
            int idx = rep * 256 + t;
            int cml = idx >> 6, d = idx & 63;
            float a = 0.f;
#pragma unroll
            for (int j = 0; j < EDGE_DIM; ++j) a += T[cml][j] * w[j * HID + d];
            TE[((size_t)l * NCOMB + comb0 + cml) * HID + d] = (f16)a;
        }
        return;
    }
    if (t < NBUCK) bcur[t] = 0;
    for (int i = t; i < 512; i += 256) gsumR[i] = 0.f;
    if (t == 0) rowptr[N_NODES] = N_EDGES;
}

// ---------------- node features + layer-0 projection (16 nodes/block)
__global__ __launch_bounds__(256) void k_nfproj(
    const int* __restrict__ xn, const float* __restrict__ emb_s,
    const float* __restrict__ emb_p, const f16* __restrict__ wcatT0,
    const float* __restrict__ bcat0,
    f16* __restrict__ q, f16* __restrict__ kv, f16* __restrict__ sk) {
    __shared__ __align__(16) f16 xs[16][72];
    int t = threadIdx.x;
    int n0 = blockIdx.x * 16;
#pragma unroll
    for (int i = 0; i < 4; ++i) {
        int idx = i * 256 + t;
        int row = idx >> 6, col = idx & 63;
        int n = n0 + row;
        float acc = 0.f;
#pragma unroll
        for (int s = 0; s < 4; ++s) {
            int id = xn[n * 4 + s];
            acc += emb_s[id * HID + col] + emb_p[s * HID + col];
        }
        xs[row][col] = (f16)acc;
    }
    __syncthreads();
    int w = t >> 6, l = t & 63;
    int rowA = l & 15;
    int kb = l >> 4;
    f16x8 a0 = *(const f16x8*)(&xs[rowA][kb << 3]);
    f16x8 a1 = *(const f16x8*)(&xs[rowA][32 + (kb << 3)]);
    int c0 = w << 6;
    int rbase = n0 + ((l >> 4) << 2);
#pragma unroll
    for (int tt = 0; tt < 4; ++tt) {
        int cl = c0 + tt * 16 + (l & 15);
        const f16* wr = wcatT0 + (cl << 6) + (kb << 3);
        f16x8 b0 = *(const f16x8*)(wr);
        f16x8 b1 = *(const f16x8*)(wr + 32);
        f32x4 z = {0.f, 0.f, 0.f, 0.f};
        z = __builtin_amdgcn_mfma_f32_16x16x32_f16(a0, b0, z, 0, 0, 0);
        z = __builtin_amdgcn_mfma_f32_16x16x32_f16(a1, b1, z, 0, 0, 0);
        float bb = bcat0[cl];
        int cc = cl & 63;
        int m = cl >> 6;
#pragma unroll
        for (int r = 0; r < 4; ++r) {
            int n = rbase + r;
            f16 val = (f16)(z[r] + bb);
            if (m == 0) q[(n << 6) + cc] = val;
            else if (m == 1) kv[(size_t)n * 128 + cc] = val;
            else if (m == 2) kv[(size_t)n * 128 + 64 + cc] = val;
            else sk[(n << 6) + cc] = val;
        }
    }
}

// ---------------- phase 1: bin edges into coarse buckets
__global__ __launch_bounds__(256) void k_bin(
    const int* __restrict__ src, const int* __restrict__ dst,
    const int* __restrict__ label, const int* __restrict__ sign,
    int* __restrict__ bcur, int2* __restrict__ buf) {
    __shared__ int hist[NBUCK];
    __shared__ int base[NBUCK];
    int t = threadIdx.x;
    for (int i = t; i < NBUCK; i += 256) hist[i] = 0;
    __syncthreads();
    int e0 = blockIdx.x * BIN_EPB;
    int pk[BIN_EPT], dl[BIN_EPT], bl[BIN_EPT], loc[BIN_EPT];
#pragma unroll
    for (int i = 0; i < BIN_EPT; ++i) {
        int e = e0 + i * 256 + t;
        bool vld = e < N_EDGES;
        int d = vld ? dst[e] : 0;
        bl[i] = d >> 8;
        dl[i] = d & 255;
        pk[i] = vld ? ((src[e] << 11) | (label[e] * NSIGN + sign[e])) : 0;
        loc[i] = vld ? atomicAdd(&hist[bl[i]], 1) : -1;
    }
    __syncthreads();
    if (t < NBUCK) {
        int h = hist[t];
        int gb = h ? atomicAdd(&bcur[t], h) : 0;
        base[t] = t * BUCK_CAP + gb;
    }
    __syncthreads();
#pragma unroll
    for (int i = 0; i < BIN_EPT; ++i)
        if (loc[i] >= 0) buf[base[bl[i]] + loc[i]] = make_int2(pk[i], dl[i]);
}

// ---------------- phase 2: inline bucket scan + per-bucket rowptr + CSR scatter
__global__ __launch_bounds__(256) void k_place(
    const int* __restrict__ bcur, const int2* __restrict__ buf,
    int* __restrict__ rowptr, int* __restrict__ scomb) {
    __shared__ int hist[256];
    __shared__ int curs[256];
    __shared__ int wsA[4];
    __shared__ int wsB[4];
    __shared__ int sbase;
    int t = threadIdx.x, b = blockIdx.x;
    int lane = t & 63, w = t >> 6;
    int v = (t < NBUCK) ? bcur[t] : 0;
    int incl = v;
#pragma unroll
    for (int o = 1; o < 64; o <<= 1) {
        int u = __shfl_up(incl, o);
        if (lane >= o) incl += u;
    }
    if (lane == 63) wsA[w] = incl;
    hist[t] = 0;
    __syncthreads();
    int woff = 0;
    for (int j = 0; j < w; ++j) woff += wsA[j];
    if (t == b) sbase = woff + incl - v;
    __syncthreads();
    int cnt = bcur[b];
    const int2* bb = buf + (size_t)b * BUCK_CAP;
    for (int i = t; i < cnt; i += 256) atomicAdd(&hist[bb[i].y], 1);
    __syncthreads();
    int hv = hist[t];
    int hincl = hv;
#pragma unroll
    for (int o = 1; o < 64; o <<= 1) {
        int u = __shfl_up(hincl, o);
        if (lane >= o) hincl += u;
    }
    if (lane == 63) wsB[w] = hincl;
    __syncthreads();
    int hoff = 0;
    for (int j = 0; j < w; ++j) hoff += wsB[j];
    int start = sbase + hoff + hincl - hv;
    int n = (b << 8) + t;
    if (n < N_NODES) rowptr[n] = start;
    curs[t] = start;
    __syncthreads();
    for (int i = t; i < cnt; i += 256) {
        int2 r = bb[i];
        int pos = atomicAdd(&curs[r.y], 1);
        scomb[pos] = r.x;
    }
}

// ---------------- MFMA projection (layers 1..5): x16 -> q, kv, sk
__global__ __launch_bounds__(256) void k_proj(
    const f16* __restrict__ x16, const f16* __restrict__ wcatT_l,
    const float* __restrict__ bcat_l,
    f16* __restrict__ q, f16* __restrict__ kv, f16* __restrict__ sk) {
    int t = threadIdx.x;
    int w = t >> 6, l = t & 63;
    int n0 = blockIdx.x * 16;
    int rowA = n0 + (l & 15);
    int kb = l >> 4;
    const f16* xr = x16 + (rowA << 6) + (kb << 3);
    f16x8 a0 = *(const f16x8*)(xr);
    f16x8 a1 = *(const f16x8*)(xr + 32);
    int c0 = w << 6;
    int rbase = n0 + ((l >> 4) << 2);
#pragma unroll
    for (int tt = 0; tt < 4; ++tt) {
        int cl = c0 + tt * 16 + (l & 15);
        const f16* wr = wcatT_l + (cl << 6) + (kb << 3);
        f16x8 b0 = *(const f16x8*)(wr);
        f16x8 b1 = *(const f16x8*)(wr + 32);
        f32x4 z = {0.f, 0.f, 0.f, 0.f};
        z = __builtin_amdgcn_mfma_f32_16x16x32_f16(a0, b0, z, 0, 0, 0);
        z = __builtin_amdgcn_mfma_f32_16x16x32_f16(a1, b1, z, 0, 0, 0);
        float bb = bcat_l[cl];
        int cc = cl & 63;
#pragma unroll
        for (int r = 0; r < 4; ++r) {
            int n = rbase + r;
            f16 val = (f16)(z[r] + bb);
            if (w == 0) q[(n << 6) + cc] = val;
            else if (w == 1) kv[(size_t)n * 128 + cc] = val;
            else if (w == 2) kv[(size_t)n * 128 + 64 + cc] = val;
            else sk[(n << 6) + cc] = val;
        }
    }
}

// ---------------- shared aggregation core: 16 edges/iter, scomb software-pipelined
#define AGG_BODY()                                                               \
    int e = lane >> 3;                                                           \
    int h = lane & 7;                                                            \
    int d = (h << 3) + e;                                                        \
    float skv = (float)sk[(n << 6) + d];                                         \
    f16x8 qf = *(const f16x8*)(q + (n << 6) + (h << 3));                         \
    int rs = rowptr[n], re = rowptr[n + 1];                                      \
    const float scale = 0.35355339059327373f;                                    \
    float lsum = 0.f;                                                            \
    float acc0 = 0.f, acc1 = 0.f, acc2 = 0.f, acc3 = 0.f;                        \
    float acc4 = 0.f, acc5 = 0.f, acc6 = 0.f, acc7 = 0.f;                        \
    bool va = rs + e < re, vb = rs + 8 + e < re;                                 \
    int pa = scomb[va ? rs + e : rs];                                            \
    int pb = scomb[vb ? rs + 8 + e : rs];                                        \
    for (int j0 = rs; j0 < re; j0 += 16) {                                       \
        bool vac = va, vbc = vb;                                                 \
        int pac = pa, pbc = pb;                                                  \
        int jn = j0 + 16;                                                        \
        va = jn + e < re;                                                        \
        vb = jn + 8 + e < re;                                                    \
        pa = scomb[va ? jn + e : rs];                                            \
        pb = scomb[vb ? jn + 8 + e : rs];                                        \
        const f16* kpa = kv + ((size_t)(pac >> 11) << 7) + (h << 3);             \
        const f16* kpb = kv + ((size_t)(pbc >> 11) << 7) + (h << 3);             \
        f16x8 ka = *(const f16x8*)(kpa);                                         \
        f16x8 vaf = *(const f16x8*)(kpa + 64);                                   \
        f16x8 ta = *(const f16x8*)(te + ((pac & 2047) << 6) + (h << 3));         \
        f16x8 kb2 = *(const f16x8*)(kpb);                                        \
        f16x8 vbf = *(const f16x8*)(kpb + 64);                                   \
        f16x8 tb = *(const f16x8*)(te + ((pbc & 2047) << 6) + (h << 3));         \
        float ala = dot8(qf, ka + ta, 0.f) * scale;                              \
        float alb = dot8(qf, kb2 + tb, 0.f) * scale;                             \
        float wa = vac ? __expf(ala) : 0.f;                                      \
        float wb = vbc ? __expf(alb) : 0.f;                                      \
        lsum += wa + wb;                                                         \
        f16x8 vta = vaf + ta;                                                    \
        f16x8 vtb = vbf + tb;                                                    \
        acc0 += wa * (float)vta[0] + wb * (float)vtb[0];                         \
        acc1 += wa * (float)vta[1] + wb * (float)vtb[1];                         \
        acc2 += wa * (float)vta[2] + wb * (float)vtb[2];                         \
        acc3 += wa * (float)vta[3] + wb * (float)vtb[3];                         \
        acc4 += wa * (float)vta[4] + wb * (float)vtb[4];                         \
        acc5 += wa * (float)vta[5] + wb * (float)vtb[5];                         \
        acc6 += wa * (float)vta[6] + wb * (float)vtb[6];                         \
        acc7 += wa * (float)vta[7] + wb * (float)vtb[7];                         \
    }                                                                            \
    _Pragma("unroll")                                                            \
    for (int o = 8; o < 64; o <<= 1) {                                           \
        lsum += __shfl_xor(lsum, o);                                             \
        acc0 += __shfl_xor(acc0, o);                                             \
        acc1 += __shfl_xor(acc1, o);                                             \
        acc2 += __shfl_xor(acc2, o);                                             \
        acc3 += __shfl_xor(acc3, o);                                             \
        acc4 += __shfl_xor(acc4, o);                                             \
        acc5 += __shfl_xor(acc5, o);                                             \
        acc6 += __shfl_xor(acc6, o);                                             \
        acc7 += __shfl_xor(acc7, o);                                             \
    }                                                                            \
    float av = acc0;                                                             \
    av = (e == 1) ? acc1 : av;                                                   \
    av = (e == 2) ? acc2 : av;                                                   \
    av = (e == 3) ? acc3 : av;                                                   \
    av = (e == 4) ? acc4 : av;                                                   \
    av = (e == 5) ? acc5 : av;                                                   \
    av = (e == 6) ? acc6 : av;                                                   \
    av = (e == 7) ? acc7 : av;                                                   \
    float outv = av / (lsum + 1e-16f) + skv;

// ---------------- aggregation + skip + LN/ReLU (layers 0..4)
__global__ __launch_bounds__(256) void k_aggL(
    const f16* __restrict__ q, const f16* __restrict__ kv,
    const f16* __restrict__ sk, const f16* __restrict__ te,
    const int* __restrict__ scomb, const int* __restrict__ rowptr,
    const float* __restrict__ ln_g, const float* __restrict__ ln_b,
    f16* __restrict__ xout) {
    int t = threadIdx.x;
    int wid = t >> 6, lane = t & 63;
    int n = blockIdx.x * 4 + wid;
    AGG_BODY()
    float ssum = outv;
#pragma unroll
    for (int o = 1; o < 64; o <<= 1) ssum += __shfl_xor(ssum, o);
    float mu = ssum * (1.f / 64.f);
    float dv = outv - mu;
    float vs = dv * dv;
#pragma unroll
    for (int o = 1; o < 64; o <<= 1) vs += __shfl_xor(vs, o);
    float var = vs * (1.f / 64.f);
    float yv = ln_g[d] * dv / sqrtf(var + EPS) + ln_b[d];
    xout[(n << 6) + d] = (f16)fmaxf(yv, 0.f);
}

// ---------------- final-layer aggregation + policy head + fused column sums
__global__ __launch_bounds__(256) void k_aggF(
    const f16* __restrict__ q, const f16* __restrict__ kv,
    const f16* __restrict__ sk, const f16* __restrict__ te,
    const int* __restrict__ scomb, const int* __restrict__ rowptr,
    const float* __restrict__ Wp, const float* __restrict__ bp,
    float* __restrict__ pol, float* __restrict__ gsumR) {
    __shared__ float sh[4][64];
    int t = threadIdx.x;
    int wid = t >> 6, lane = t & 63;
    int n = blockIdx.x * 4 + wid;
    AGG_BODY()
    float p0 = outv * Wp[d * 2 + 0];
    float p1 = outv * Wp[d * 2 + 1];
#pragma unroll
    for (int o = 1; o < 64; o <<= 1) {
        p0 += __shfl_xor(p0, o);
        p1 += __shfl_xor(p1, o);
    }
    if (lane == 0) {
        pol[n * 2 + 0] = p0 + bp[0];
        pol[n * 2 + 1] = p1 + bp[1];
    }
    sh[wid][d] = outv;
    __syncthreads();
    if (wid == 0) {
        float s = sh[0][lane] + sh[1][lane] + sh[2][lane] + sh[3][lane];
        atomicAdd(&gsumR[((blockIdx.x & 7) << 6) + lane], s);
    }
}

// ---------------- value head
__global__ __launch_bounds__(64) void k_value(
    const float* __restrict__ gsumR, const float* __restrict__ Wv1,
    const float* __restrict__ bv1, const float* __restrict__ Wv2,
    const float* __restrict__ bv2, float* __restrict__ out) {
    int lane = threadIdx.x;
    __shared__ float g[64];
    float gs = 0.f;
#pragma unroll
    for (int r = 0; r < 8; ++r) gs += gsumR[(r << 6) + lane];
    g[lane] = gs * (1.f / N_NODES);
    __syncthreads();
    float h = bv1[lane];
    for (int i = 0; i < HID; ++i) h += g[i] * Wv1[i * HID + lane];
    h = fmaxf(h, 0.f);
    float p = h * Wv2[lane];
#pragma unroll
    for (int o = 1; o < 64; o <<= 1) p += __shfl_xor(p, o);
    if (lane == 0) out[0] = tanhf(p + bv2[0]);
}

extern "C" void kernel_launch(void* const* d_in, const int* in_sizes, int n_in,
                              void* d_out, int out_size, void* d_ws, size_t ws_size,
                              hipStream_t stream) {
    const int* x_nodes = (const int*)d_in[0];
    const int* edge_index = (const int*)d_in[1];
    const int* edge_label = (const int*)d_in[2];
    const int* edge_sign = (const int*)d_in[3];
    const float* emb_strand = (const float*)d_in[4];
    const float* emb_pos = (const float*)d_in[5];
    const float* emb_sign = (const float*)d_in[6];
    const float* We = (const float*)d_in[7];
    const float* be = (const float*)d_in[8];
    const float* Wq = (const float*)d_in[9];
    const float* bq = (const float*)d_in[10];
    const float* Wk = (const float*)d_in[11];
    const float* bk = (const float*)d_in[12];
    const float* Wv = (const float*)d_in[13];
    const float* bv = (const float*)d_in[14];
    const float* Wedge = (const float*)d_in[15];
    const float* Wskip = (const float*)d_in[16];
    const float* bskip = (const float*)d_in[17];
    const float* ln_g = (const float*)d_in[18];
    const float* ln_b = (const float*)d_in[19];
    const float* Wp = (const float*)d_in[20];
    const float* bp = (const float*)d_in[21];
    const float* Wv1 = (const float*)d_in[22];
    const float* bv1 = (const float*)d_in[23];
    const float* Wv2 = (const float*)d_in[24];
    const float* bv2 = (const float*)d_in[25];
    float* out = (float*)d_out;

    const int* src = edge_index;
    const int* dst = edge_index + N_EDGES;

    char* ws = (char*)d_ws;
    size_t off = 0;
    auto alloc = [&](size_t bytes) -> void* {
        void* p = ws + off;
        off += (bytes + 255) & ~(size_t)255;
        return p;
    };
    f16* x16 = (f16*)alloc((size_t)N_NODES * HID * 2);
    f16* q = (f16*)alloc((size_t)N_NODES * HID * 2);
    f16* kv = (f16*)alloc((size_t)N_NODES * 128 * 2);
    f16* sk = (f16*)alloc((size_t)N_NODES * HID * 2);
    int* scomb = (int*)alloc((size_t)N_EDGES * 4);
    int2* binbuf = (int2*)alloc((size_t)NBUCK * BUCK_CAP * 8);
    int* rowptr = (int*)alloc((size_t)(N_NODES + 1) * 4);
    int* bcur = (int*)alloc((size_t)NBUCK * 4);
    f16* TE = (f16*)alloc((size_t)LAYERS * NCOMB * HID * 2);
    f16* wcatT = (f16*)alloc((size_t)LAYERS * 256 * HID * 2);
    float* bcat = (float*)alloc((size_t)LAYERS * 256 * 4);
    float* gsumR = (float*)alloc(512 * 4);

    k_prep<<<PREP_BLK, 256, 0, stream>>>(
        Wq, bq, Wk, bk, Wv, bv, Wskip, bskip, wcatT, bcat,
        emb_strand, emb_sign, We, be, Wedge, TE, bcur, rowptr, gsumR);
    k_nfproj<<<N_NODES / 16, 256, 0, stream>>>(
        x_nodes, emb_strand, emb_pos, wcatT, bcat, q, kv, sk);
    k_bin<<<BIN_NBLK, 256, 0, stream>>>(src, dst, edge_label, edge_sign, bcur, binbuf);
    k_place<<<NBUCK, 256, 0, stream>>>(bcur, binbuf, rowptr, scomb);

    for (int l = 0; l < LAYERS - 1; ++l) {
        k_aggL<<<N_NODES / 4, 256, 0, stream>>>(
            q, kv, sk, TE + (size_t)l * NCOMB * HID, scomb, rowptr,
            ln_g + (size_t)l * HID, ln_b + (size_t)l * HID, x16);
        k_proj<<<N_NODES / 16, 256, 0, stream>>>(
            x16, wcatT + (size_t)(l + 1) * 256 * HID, bcat + (size_t)(l + 1) * 256,
            q, kv, sk);
    }
    k_aggF<<<N_NODES / 4, 256, 0, stream>>>(
        q, kv, sk, TE + (size_t)(LAYERS - 1) * NCOMB * HID, scomb, rowptr,
        Wp, bp, out, gsumR);
    k_value<<<1, 64, 0, stream>>>(gsumR, Wv1, bv1, Wv2, bv2, out + 2 * N_NODES);
}